// Round 5
// baseline (121.369 us; speedup 1.0000x reference)
//
#include <hip/hip_runtime.h>
#include <math.h>

#define BQ 8192
#define HD 1024
#define NE 8

#define BM 64
#define BN 128
#define BK 32

// ---------------- workspace layout (bytes) ----------------
#define WS_IDX      0           // int[BQ]
#define WS_ROWLIST  32768       // int[BQ]
#define WS_COUNT    65536       // int[NE]
#define WS_BASE     65568       // int[NE]
#define WS_CURSOR   65600       // int[NE]
#define WS_S        65632       // float[NE]
#define WS_ZSUM     65664       // float
#define WS_CESUM    65668       // float
#define WS_TICKET   65672       // int
#define WS_ZPAD     65728       // 128B zero scratch (GEMM tile-tail rows)
#define WS_LOGITS2  65856       // float[BQ*2]
#define WS_HEAD     131392      // memset size
#define WS_XC       131392      // bf16 compacted x [BQ][HD] = 16MB
#define WS_W1T      16908784    // bf16 w1^T [NE][n][k] = 16MB

using f32x4  = __attribute__((ext_vector_type(4))) float;
using bf16x8 = __attribute__((ext_vector_type(8))) __bf16;

__device__ __forceinline__ float gelu_exact(float v) {
    return 0.5f * v * (1.0f + erff(v * 0.70710678118654752440f));
}

__device__ __forceinline__ unsigned short f2bf(float f) {
    union { float f; unsigned int u; } v; v.f = f;
    unsigned int u = v.u;
    unsigned int r = (u + 0x7FFFu + ((u >> 16) & 1u)) >> 16;
    return (unsigned short)r;
}

__device__ __forceinline__ void gll16(const void* g, void* l) {
    __builtin_amdgcn_global_load_lds((const __attribute__((address_space(1))) void*)g,
                                     (__attribute__((address_space(3))) void*)l, 16, 0, 0);
}

// ---------------- router + (last block) prefix ----------------
__global__ __launch_bounds__(256) void router_kernel(
    const float* __restrict__ x, const float* __restrict__ gate_w,
    int* __restrict__ idx, int* __restrict__ count,
    float* __restrict__ S, float* __restrict__ zsum,
    int* __restrict__ ticket, int* __restrict__ base, int* __restrict__ cursor)
{
    __shared__ float gw[NE * HD];   // 32 KB
    __shared__ float sS[NE];
    __shared__ float sZ;
    __shared__ int   sC[NE];

    int tid = threadIdx.x;
    for (int i = tid * 4; i < NE * HD; i += 256 * 4) {
        *(float4*)(gw + i) = *(const float4*)(gate_w + i);
    }
    if (tid < NE) { sS[tid] = 0.f; sC[tid] = 0; }
    if (tid == 0) sZ = 0.f;
    __syncthreads();

    int wave = tid >> 6, lane = tid & 63;
    float accS[NE];
    int   accC[NE];
    #pragma unroll
    for (int e = 0; e < NE; e++) { accS[e] = 0.f; accC[e] = 0; }
    float accZ = 0.f;

    int waveId = blockIdx.x * 4 + wave;     // 0..1023
    for (int r = waveId; r < BQ; r += gridDim.x * 4) {
        const float* xr = x + (size_t)r * HD;
        float acc[NE];
        #pragma unroll
        for (int e = 0; e < NE; e++) acc[e] = 0.f;
        #pragma unroll
        for (int it = 0; it < HD / 256; it++) {
            int k = lane * 4 + it * 256;
            float4 xv = *(const float4*)(xr + k);
            #pragma unroll
            for (int e = 0; e < NE; e++) {
                const float* g = gw + e * HD + k;
                acc[e] += xv.x * g[0] + xv.y * g[1] + xv.z * g[2] + xv.w * g[3];
            }
        }
        #pragma unroll
        for (int e = 0; e < NE; e++) {
            #pragma unroll
            for (int off = 32; off > 0; off >>= 1)
                acc[e] += __shfl_xor(acc[e], off);
        }
        if (lane == 0) {
            float m = acc[0]; int bi = 0;
            #pragma unroll
            for (int e = 1; e < NE; e++) if (acc[e] > m) { m = acc[e]; bi = e; }
            float se = 0.f, ex[NE];
            #pragma unroll
            for (int e = 0; e < NE; e++) { ex[e] = expf(acc[e] - m); se += ex[e]; }
            float inv = 1.f / se;
            #pragma unroll
            for (int e = 0; e < NE; e++) accS[e] += ex[e] * inv;
            float lse = m + logf(se);
            accZ += lse * lse;
            accC[bi] += 1;
            idx[r] = bi;
        }
    }
    if (lane == 0) {
        #pragma unroll
        for (int e = 0; e < NE; e++) {
            atomicAdd(&sS[e], accS[e]);
            if (accC[e]) atomicAdd(&sC[e], accC[e]);
        }
        atomicAdd(&sZ, accZ);
    }
    __syncthreads();
    if (tid < NE) {
        atomicAdd(&S[tid], sS[tid]);
        atomicAdd(&count[tid], sC[tid]);
    }
    if (tid == 0) atomicAdd(zsum, sZ);

    // folded prefix: last block to finish computes base/cursor
    __threadfence();
    __syncthreads();
    if (tid == 0) {
        if (atomicAdd(ticket, 1) == (int)gridDim.x - 1) {
            __threadfence();
            int acc = 0;
            for (int e = 0; e < NE; e++) {
                int c = atomicAdd(&count[e], 0);
                base[e] = acc; cursor[e] = acc; acc += c;
            }
            __threadfence();
        }
    }
}

// ---------------- w1 fp32 [e][k][n] -> bf16 [e][n][k] ----------------
__global__ __launch_bounds__(256) void w1_transpose_kernel(
    const float* __restrict__ w1, unsigned short* __restrict__ w1t)
{
    __shared__ unsigned short lt[64][72];   // [n][k], padded
    int t = threadIdx.x;
    int e = blockIdx.z;
    int k0 = blockIdx.y * 64, n0 = blockIdx.x * 64;
    const float* src = w1 + ((size_t)e << 20) + (size_t)k0 * HD + n0;
    #pragma unroll
    for (int s = 0; s < 4; s++) {
        int q = t + s * 256;
        int kk = q >> 4;
        int n4 = q & 15;
        float4 v = *(const float4*)(src + (size_t)kk * HD + n4 * 4);
        lt[n4 * 4 + 0][kk] = f2bf(v.x);
        lt[n4 * 4 + 1][kk] = f2bf(v.y);
        lt[n4 * 4 + 2][kk] = f2bf(v.z);
        lt[n4 * 4 + 3][kk] = f2bf(v.w);
    }
    __syncthreads();
    unsigned short* dst = w1t + ((size_t)e << 20) + (size_t)n0 * HD + k0;
    #pragma unroll
    for (int s = 0; s < 4; s++) {
        int q = t + s * 256;
        int nn = q >> 4;
        int kq = q & 15;
        *(ushort4*)(dst + (size_t)nn * HD + kq * 4) = *(ushort4*)&lt[nn][kq * 4];
    }
}

// ---------------- scatter / compaction index ----------------
__global__ __launch_bounds__(256) void scatter_kernel(
    const int* __restrict__ idx, int* __restrict__ cursor, int* __restrict__ rowlist)
{
    __shared__ int loc[NE];
    __shared__ int basev[NE];
    int tid = threadIdx.x;
    int r = blockIdx.x * 256 + tid;
    if (tid < NE) loc[tid] = 0;
    __syncthreads();
    int e = idx[r];
    int my = atomicAdd(&loc[e], 1);
    __syncthreads();
    if (tid < NE) basev[tid] = atomicAdd(&cursor[tid], loc[tid]);
    __syncthreads();
    rowlist[basev[e] + my] = r;
}

// ---------------- compact rows: xc[p] = bf16(x[rowlist[p]]) ----------------
// one wave per row, grid 2048 x 256
__global__ __launch_bounds__(256) void compact_kernel(
    const float* __restrict__ x, const int* __restrict__ rowlist,
    unsigned short* __restrict__ xc)
{
    int p = (blockIdx.x * 256 + threadIdx.x) >> 6;  // 0..8191
    int lane = threadIdx.x & 63;
    int row = rowlist[p];
    const float* src = x + (size_t)row * HD;
    unsigned short* dst = xc + (size_t)p * HD;
    #pragma unroll
    for (int i = 0; i < 4; i++) {
        int k = lane * 4 + i * 256;
        float4 v = *(const float4*)(src + k);
        ushort4 o;
        o.x = f2bf(v.x); o.y = f2bf(v.y); o.z = f2bf(v.z); o.w = f2bf(v.w);
        *(ushort4*)(dst + k) = o;
    }
}

// ---------------- MFMA expert GEMM: contiguous A, triple-buffer, counted vmcnt --
// grid (8, 32, 8), 256 threads = 4 waves (2x2), wave tile 32x64.
__global__ __launch_bounds__(256, 4) void expert_gemm_kernel(
    const unsigned short* __restrict__ xc, const unsigned short* __restrict__ w1t,
    const float* __restrict__ b1, const float* __restrict__ w2,
    const int* __restrict__ rowlist, const int* __restrict__ base,
    const int* __restrict__ count, float* __restrict__ logits2,
    const char* __restrict__ zeropad)
{
    int e = blockIdx.z;
    int cnt = count[e];
    int rt = blockIdx.y;
    if (rt * BM >= cnt) return;
    int n0 = blockIdx.x * BN;
    int bse = base[e];

    // 3 buffers x [A 4KB | B 8KB]
    __shared__ __align__(16) char lds[3][12288];

    int t = threadIdx.x;
    int l = t & 63;

    // pre-swizzled source slot (rule 21): slot' = slot ^ ((row>>1)&3); row = t>>2
    int scolb = ((t & 3) ^ ((t >> 3) & 3)) << 4;

    // A source: contiguous compacted row bse + rt*64 + (t>>2)
    int m = t >> 2;
    const char* srcA; int stepA;
    if (rt * BM + m < cnt) {
        srcA = (const char*)xc + (size_t)(bse + rt * BM + m) * (HD * 2) + scolb;
        stepA = BK * 2;
    } else {
        srcA = zeropad + scolb;         // tile-tail row (next expert's data otherwise)
        stepA = 0;
    }

    const char* w1tp = (const char*)w1t + ((size_t)e << 21);
    const char* srcB0 = w1tp + (size_t)(n0 + m) * (HD * 2) + scolb;
    const char* srcB1 = w1tp + (size_t)(n0 + 64 + m) * (HD * 2) + scolb;

    int wid = t >> 6;
    int wr = wid >> 1, wc = wid & 1;
    int r = l & 15, h = l >> 4;
    int off = (h * 16) ^ (((r >> 1) & 3) << 4);   // swizzled k-slot on read side

    f32x4 acc[2][4];
    #pragma unroll
    for (int i = 0; i < 2; i++)
        #pragma unroll
        for (int j = 0; j < 4; j++) acc[i][j] = (f32x4)(0.f);

    auto stage = [&](int bi) {
        char* a = lds[bi] + t * 16;
        char* b = lds[bi] + 4096 + t * 16;
        gll16(srcA,  a);        srcA  += stepA;
        gll16(srcB0, b);        srcB0 += BK * 2;
        gll16(srcB1, b + 4096); srcB1 += BK * 2;
    };

    auto compute = [&](int bi) {
        const char* Ar = lds[bi] + (wr * 32 + r) * 64;
        const char* Br = lds[bi] + 4096 + (wc * 64 + r) * 64;
        bf16x8 a0  = *(const bf16x8*)(Ar + off);
        bf16x8 a1  = *(const bf16x8*)(Ar + 1024 + off);
        bf16x8 b0  = *(const bf16x8*)(Br + off);
        bf16x8 b1r = *(const bf16x8*)(Br + 1024 + off);
        bf16x8 b2r = *(const bf16x8*)(Br + 2048 + off);
        bf16x8 b3r = *(const bf16x8*)(Br + 3072 + off);
        acc[0][0] = __builtin_amdgcn_mfma_f32_16x16x32_bf16(a0, b0,  acc[0][0], 0, 0, 0);
        acc[0][1] = __builtin_amdgcn_mfma_f32_16x16x32_bf16(a0, b1r, acc[0][1], 0, 0, 0);
        acc[0][2] = __builtin_amdgcn_mfma_f32_16x16x32_bf16(a0, b2r, acc[0][2], 0, 0, 0);
        acc[0][3] = __builtin_amdgcn_mfma_f32_16x16x32_bf16(a0, b3r, acc[0][3], 0, 0, 0);
        acc[1][0] = __builtin_amdgcn_mfma_f32_16x16x32_bf16(a1, b0,  acc[1][0], 0, 0, 0);
        acc[1][1] = __builtin_amdgcn_mfma_f32_16x16x32_bf16(a1, b1r, acc[1][1], 0, 0, 0);
        acc[1][2] = __builtin_amdgcn_mfma_f32_16x16x32_bf16(a1, b2r, acc[1][2], 0, 0, 0);
        acc[1][3] = __builtin_amdgcn_mfma_f32_16x16x32_bf16(a1, b3r, acc[1][3], 0, 0, 0);
    };

    // pipeline: 32 K-steps, 3 buffers, loads get ~2 iterations to land.
    // body order (race-safe): vmcnt(3) -> barrier -> stage(it+2) -> compute(it)
    stage(0); stage(1);                         // 6 outstanding
    int cs = 2, cc = 0;
    #pragma unroll 1
    for (int it = 0; it < HD / BK - 2; ++it) {
        asm volatile("s_waitcnt vmcnt(3)" ::: "memory");   // oldest tile landed
        __builtin_amdgcn_s_barrier();
        stage(cs); cs = (cs == 2) ? 0 : cs + 1;
        compute(cc); cc = (cc == 2) ? 0 : cc + 1;
    }
    asm volatile("s_waitcnt vmcnt(3)" ::: "memory");
    __builtin_amdgcn_s_barrier();
    compute(cc); cc = (cc == 2) ? 0 : cc + 1;
    asm volatile("s_waitcnt vmcnt(0)" ::: "memory");
    __builtin_amdgcn_s_barrier();
    compute(cc);

    // epilogue: bias + gelu + w2 partial dot + 16-lane reduce
    float b1v[4], w20v[4], w21v[4];
    #pragma unroll
    for (int j = 0; j < 4; j++) {
        int col = n0 + wc * 64 + j * 16 + r;
        b1v[j]  = b1[e * HD + col];
        w20v[j] = w2[((size_t)e * HD + col) * 2 + 0];
        w21v[j] = w2[((size_t)e * HD + col) * 2 + 1];
    }
    #pragma unroll
    for (int i = 0; i < 2; i++) {
        #pragma unroll
        for (int reg = 0; reg < 4; reg++) {
            float s0 = 0.f, s1 = 0.f;
            #pragma unroll
            for (int j = 0; j < 4; j++) {
                float hv = gelu_exact(acc[i][j][reg] + b1v[j]);
                s0 += hv * w20v[j];
                s1 += hv * w21v[j];
            }
            #pragma unroll
            for (int offx = 1; offx < 16; offx <<= 1) {
                s0 += __shfl_xor(s0, offx);
                s1 += __shfl_xor(s1, offx);
            }
            if (r == 0) {
                int lm = wr * 32 + i * 16 + 4 * h + reg;
                int p2 = rt * BM + lm;
                if (p2 < cnt) {
                    int row = rowlist[bse + p2];
                    atomicAdd(&logits2[row * 2 + 0], s0);
                    atomicAdd(&logits2[row * 2 + 1], s1);
                }
            }
        }
    }
}

// ---------------- CE over (softmaxed) expert outputs ----------------
__global__ __launch_bounds__(256) void ce_kernel(
    const float* __restrict__ logits2, const float* __restrict__ b2,
    const int* __restrict__ idx, const int* __restrict__ label,
    float* __restrict__ cesum)
{
    __shared__ float red[4];
    int tid = threadIdx.x;
    int r = blockIdx.x * 256 + tid;
    int e = idx[r];
    float l0 = logits2[r * 2 + 0] + b2[e * 2 + 0];
    float l1 = logits2[r * 2 + 1] + b2[e * 2 + 1];
    float m = fmaxf(l0, l1);
    float e0 = expf(l0 - m), e1 = expf(l1 - m);
    float inv = 1.f / (e0 + e1);
    float p0 = e0 * inv, p1 = e1 * inv;
    float m2 = fmaxf(p0, p1);
    float z = m2 + logf(expf(p0 - m2) + expf(p1 - m2));
    float lp = ((label[r] == 0) ? p0 : p1) - z;
    float ce = -lp;

    int lane = tid & 63, wave = tid >> 6;
    #pragma unroll
    for (int off = 32; off > 0; off >>= 1) ce += __shfl_xor(ce, off);
    if (lane == 0) red[wave] = ce;
    __syncthreads();
    if (tid == 0) atomicAdd(cesum, red[0] + red[1] + red[2] + red[3]);
}

// ---------------- finalize ----------------
__global__ void finalize_kernel(const float* __restrict__ S, const int* __restrict__ count,
                                const float* __restrict__ zsum, const float* __restrict__ cesum,
                                float* __restrict__ out)
{
    if (threadIdx.x == 0 && blockIdx.x == 0) {
        float bal = 0.f;
        for (int e = 0; e < NE; e++) bal += S[e] * (float)count[e];
        bal *= (float)NE / ((float)BQ * (float)BQ);
        out[0] = cesum[0] / (float)BQ + 0.01f * bal + 0.001f * (zsum[0] / (float)BQ);
    }
}

extern "C" void kernel_launch(void* const* d_in, const int* in_sizes, int n_in,
                              void* d_out, int out_size, void* d_ws, size_t ws_size,
                              hipStream_t stream) {
    const float* x      = (const float*)d_in[0];
    const int*   label  = (const int*)d_in[1];
    const float* gate_w = (const float*)d_in[2];
    const float* w1     = (const float*)d_in[3];
    const float* b1     = (const float*)d_in[4];
    const float* w2     = (const float*)d_in[5];
    const float* b2     = (const float*)d_in[6];
    float* out = (float*)d_out;

    char* ws = (char*)d_ws;
    int*   idx     = (int*)(ws + WS_IDX);
    int*   rowlist = (int*)(ws + WS_ROWLIST);
    int*   count   = (int*)(ws + WS_COUNT);
    int*   base    = (int*)(ws + WS_BASE);
    int*   cursor  = (int*)(ws + WS_CURSOR);
    float* S       = (float*)(ws + WS_S);
    float* zsum    = (float*)(ws + WS_ZSUM);
    float* cesum   = (float*)(ws + WS_CESUM);
    int*   ticket  = (int*)(ws + WS_TICKET);
    float* logits2 = (float*)(ws + WS_LOGITS2);
    const char* zeropad = (const char*)(ws + WS_ZPAD);
    unsigned short* xc  = (unsigned short*)(ws + WS_XC);
    unsigned short* w1t = (unsigned short*)(ws + WS_W1T);

    hipMemsetAsync(d_ws, 0, WS_HEAD, stream);

    router_kernel<<<256, 256, 0, stream>>>(x, gate_w, idx, count, S, zsum,
                                           ticket, base, cursor);
    w1_transpose_kernel<<<dim3(16, 16, 8), 256, 0, stream>>>(w1, w1t);
    scatter_kernel<<<BQ / 256, 256, 0, stream>>>(idx, cursor, rowlist);
    compact_kernel<<<BQ / 4, 256, 0, stream>>>(x, rowlist, xc);
    expert_gemm_kernel<<<dim3(HD / BN, 32, NE), 256, 0, stream>>>(
        xc, w1t, b1, w2, rowlist, base, count, logits2, zeropad);
    ce_kernel<<<BQ / 256, 256, 0, stream>>>(logits2, b2, idx, label, cesum);
    finalize_kernel<<<1, 64, 0, stream>>>(S, count, zsum, cesum, out);
}

// Round 6
// 118.215 us; speedup vs baseline: 1.0267x; 1.0267x over previous
//
#include <hip/hip_runtime.h>
#include <math.h>

#define BQ 8192
#define HD 1024
#define NE 8

#define BM 64
#define BN 128
#define BK 32

// ---------------- workspace layout (bytes) ----------------
#define WS_IDX      0           // int[BQ]
#define WS_ROWLIST  32768       // int[BQ]  compacted p -> original row
#define WS_DEST     65536       // int[BQ]  original row -> compacted p
#define WS_COUNT    98304       // int[NE]
#define WS_BASE     98336       // int[NE]
#define WS_CURSOR   98368       // int[NE]
#define WS_S        98400       // float[NE]
#define WS_ZSUM     98432       // float
#define WS_CESUM    98436       // float
#define WS_TICKET   98440       // int
#define WS_LOGITS2  98464       // float[BQ*2] (compacted order)
#define WS_HEAD     164032      // memset size
#define WS_XC       164032      // bf16 compacted x [BQ][HD] = 16MB
#define WS_W1T      16941248    // bf16 w1^T [NE][n][k] = 16MB

using f32x4  = __attribute__((ext_vector_type(4))) float;
using bf16x8 = __attribute__((ext_vector_type(8))) __bf16;

__device__ __forceinline__ float gelu_exact(float v) {
    return 0.5f * v * (1.0f + erff(v * 0.70710678118654752440f));
}

__device__ __forceinline__ unsigned short f2bf(float f) {
    union { float f; unsigned int u; } v; v.f = f;
    unsigned int u = v.u;
    unsigned int r = (u + 0x7FFFu + ((u >> 16) & 1u)) >> 16;
    return (unsigned short)r;
}

__device__ __forceinline__ void gll16(const void* g, void* l) {
    __builtin_amdgcn_global_load_lds((const __attribute__((address_space(1))) void*)g,
                                     (__attribute__((address_space(3))) void*)l, 16, 0, 0);
}

// ---------------- prep: router (blocks 0..255) || w1 transpose (256..2303) ----
__global__ __launch_bounds__(256) void prep_kernel(
    const float* __restrict__ x, const float* __restrict__ gate_w,
    const float* __restrict__ w1,
    int* __restrict__ idx, int* __restrict__ count,
    float* __restrict__ S, float* __restrict__ zsum,
    int* __restrict__ ticket, int* __restrict__ base, int* __restrict__ cursor,
    unsigned short* __restrict__ w1t)
{
    __shared__ __align__(16) char smem[33024];
    int tid = threadIdx.x;

    if (blockIdx.x >= 256) {
        // ---- transpose role: w1 fp32 [e][k][n] -> bf16 [e][n][k], 64x64 tile
        unsigned short (*lt)[72] = (unsigned short (*)[72])smem;
        int tile = blockIdx.x - 256;          // 0..2047
        int e = tile >> 8;
        int rem = tile & 255;
        int k0 = (rem >> 4) << 6, n0 = (rem & 15) << 6;
        const float* src = w1 + ((size_t)e << 20) + (size_t)k0 * HD + n0;
        #pragma unroll
        for (int s = 0; s < 4; s++) {
            int q = tid + s * 256;
            int kk = q >> 4, n4 = q & 15;
            float4 v = *(const float4*)(src + (size_t)kk * HD + n4 * 4);
            lt[n4 * 4 + 0][kk] = f2bf(v.x);
            lt[n4 * 4 + 1][kk] = f2bf(v.y);
            lt[n4 * 4 + 2][kk] = f2bf(v.z);
            lt[n4 * 4 + 3][kk] = f2bf(v.w);
        }
        __syncthreads();
        unsigned short* dst = w1t + ((size_t)e << 20) + (size_t)n0 * HD + k0;
        #pragma unroll
        for (int s = 0; s < 4; s++) {
            int q = tid + s * 256;
            int nn = q >> 4, kq = q & 15;
            *(ushort4*)(dst + (size_t)nn * HD + kq * 4) = *(ushort4*)&lt[nn][kq * 4];
        }
        return;
    }

    // ---- router role
    float* gw = (float*)smem;                       // 32 KB
    float* sS = (float*)(smem + 32768);             // NE floats
    int*   sC = (int*)(smem + 32768 + 32);          // NE ints
    float* sZ = (float*)(smem + 32768 + 64);        // 1 float

    for (int i = tid * 4; i < NE * HD; i += 256 * 4) {
        *(float4*)(gw + i) = *(const float4*)(gate_w + i);
    }
    if (tid < NE) { sS[tid] = 0.f; sC[tid] = 0; }
    if (tid == 0) sZ[0] = 0.f;
    __syncthreads();

    int wave = tid >> 6, lane = tid & 63;
    float accS[NE];
    int   accC[NE];
    #pragma unroll
    for (int e = 0; e < NE; e++) { accS[e] = 0.f; accC[e] = 0; }
    float accZ = 0.f;

    int waveId = blockIdx.x * 4 + wave;     // 0..1023
    for (int r = waveId; r < BQ; r += 1024) {
        const float* xr = x + (size_t)r * HD;
        float acc[NE];
        #pragma unroll
        for (int e = 0; e < NE; e++) acc[e] = 0.f;
        #pragma unroll
        for (int it = 0; it < HD / 256; it++) {
            int k = lane * 4 + it * 256;
            float4 xv = *(const float4*)(xr + k);
            #pragma unroll
            for (int e = 0; e < NE; e++) {
                const float* g = gw + e * HD + k;
                acc[e] += xv.x * g[0] + xv.y * g[1] + xv.z * g[2] + xv.w * g[3];
            }
        }
        #pragma unroll
        for (int e = 0; e < NE; e++) {
            #pragma unroll
            for (int off = 32; off > 0; off >>= 1)
                acc[e] += __shfl_xor(acc[e], off);
        }
        if (lane == 0) {
            float m = acc[0]; int bi = 0;
            #pragma unroll
            for (int e = 1; e < NE; e++) if (acc[e] > m) { m = acc[e]; bi = e; }
            float se = 0.f, ex[NE];
            #pragma unroll
            for (int e = 0; e < NE; e++) { ex[e] = expf(acc[e] - m); se += ex[e]; }
            float inv = 1.f / se;
            #pragma unroll
            for (int e = 0; e < NE; e++) accS[e] += ex[e] * inv;
            float lse = m + logf(se);
            accZ += lse * lse;
            accC[bi] += 1;
            idx[r] = bi;
        }
    }
    if (lane == 0) {
        #pragma unroll
        for (int e = 0; e < NE; e++) {
            atomicAdd(&sS[e], accS[e]);
            if (accC[e]) atomicAdd(&sC[e], accC[e]);
        }
        atomicAdd(sZ, accZ);
    }
    __syncthreads();
    if (tid < NE) {
        atomicAdd(&S[tid], sS[tid]);
        atomicAdd(&count[tid], sC[tid]);
    }
    if (tid == 0) atomicAdd(zsum, sZ[0]);

    // folded prefix: last router block computes base/cursor
    __threadfence();
    __syncthreads();
    if (tid == 0) {
        if (atomicAdd(ticket, 1) == 255) {
            __threadfence();
            int acc = 0;
            for (int e = 0; e < NE; e++) {
                int c = atomicAdd(&count[e], 0);
                base[e] = acc; cursor[e] = acc; acc += c;
            }
            __threadfence();
        }
    }
}

// ---------------- scatter: build rowlist (p->r) and dest (r->p) ----------------
__global__ __launch_bounds__(256) void scatter_kernel(
    const int* __restrict__ idx, int* __restrict__ cursor,
    int* __restrict__ rowlist, int* __restrict__ dest)
{
    __shared__ int loc[NE];
    __shared__ int basev[NE];
    int tid = threadIdx.x;
    int r = blockIdx.x * 256 + tid;
    if (tid < NE) loc[tid] = 0;
    __syncthreads();
    int e = idx[r];
    int my = atomicAdd(&loc[e], 1);
    __syncthreads();
    if (tid < NE) basev[tid] = atomicAdd(&cursor[tid], loc[tid]);
    __syncthreads();
    int pos = basev[e] + my;
    rowlist[pos] = r;
    dest[r] = pos;
}

// ---------------- compact: xc[dest[r]] = bf16(x[r]) (sequential reads) --------
__global__ __launch_bounds__(256) void compact_kernel(
    const float* __restrict__ x, const int* __restrict__ dest,
    unsigned short* __restrict__ xc)
{
    int r = (blockIdx.x * 256 + threadIdx.x) >> 6;  // 0..8191
    int lane = threadIdx.x & 63;
    int pos = dest[r];
    const float* src = x + (size_t)r * HD;
    unsigned short* dst = xc + (size_t)pos * HD;
    #pragma unroll
    for (int i = 0; i < 4; i++) {
        int k = lane * 4 + i * 256;
        float4 v = *(const float4*)(src + k);
        ushort4 o;
        o.x = f2bf(v.x); o.y = f2bf(v.y); o.z = f2bf(v.z); o.w = f2bf(v.w);
        *(ushort4*)(dst + k) = o;
    }
}

// ---------------- MFMA expert GEMM: global row tiling, all blocks active ------
// grid 1024 linear: col = wg&7 (XCD-pinned), rt = wg>>3. 4 waves, wave 32x64.
__global__ __launch_bounds__(256, 4) void expert_gemm_kernel(
    const unsigned short* __restrict__ xc, const unsigned short* __restrict__ w1t,
    const float* __restrict__ b1, const float* __restrict__ w2,
    const int* __restrict__ base, float* __restrict__ logits2c)
{
    int wg = blockIdx.x;
    int n0 = (wg & 7) * BN;
    int p0 = (wg >> 3) * BM;

    // expert range covered by rows [p0, p0+63] (static-index scan)
    int e0 = 0, e1 = 0;
    {
        int b1v_, b2v_, b3v_, b4v_, b5v_, b6v_, b7v_;
        b1v_ = base[1]; b2v_ = base[2]; b3v_ = base[3]; b4v_ = base[4];
        b5v_ = base[5]; b6v_ = base[6]; b7v_ = base[7];
        int pe = p0 + BM - 1;
        e0 = (p0 >= b1v_) + (p0 >= b2v_) + (p0 >= b3v_) + (p0 >= b4v_)
           + (p0 >= b5v_) + (p0 >= b6v_) + (p0 >= b7v_);
        e1 = (pe >= b1v_) + (pe >= b2v_) + (pe >= b3v_) + (pe >= b4v_)
           + (pe >= b5v_) + (pe >= b6v_) + (pe >= b7v_);
    }

    // 3 buffers x [A 4KB | B 8KB]
    __shared__ __align__(16) char lds[3][12288];

    int t = threadIdx.x;
    int l = t & 63;
    // pre-swizzled source slot (rule 21): slot' = slot ^ ((row>>1)&3), row=t>>2
    int scolb = ((t & 3) ^ ((t >> 3) & 3)) << 4;
    int m = t >> 2;

    const char* srcA0 = (const char*)xc + (size_t)(p0 + m) * (HD * 2) + scolb;

    int wid = t >> 6;
    int wr = wid >> 1, wc = wid & 1;
    int r = l & 15, h = l >> 4;
    int off = (h * 16) ^ (((r >> 1) & 3) << 4);

    #pragma unroll 1
    for (int e = e0; e <= e1; ++e) {
        f32x4 acc[2][4];
        #pragma unroll
        for (int i = 0; i < 2; i++)
            #pragma unroll
            for (int j = 0; j < 4; j++) acc[i][j] = (f32x4)(0.f);

        const char* sA = srcA0;
        const char* w1tp = (const char*)w1t + ((size_t)e << 21);
        const char* sB0 = w1tp + (size_t)(n0 + m) * (HD * 2) + scolb;
        const char* sB1 = sB0 + (size_t)64 * (HD * 2);

        auto stage = [&](int bi) {
            gll16(sA,  lds[bi] + t * 16);        sA  += BK * 2;
            gll16(sB0, lds[bi] + 4096 + t * 16); sB0 += BK * 2;
            gll16(sB1, lds[bi] + 8192 + t * 16); sB1 += BK * 2;
        };
        auto compute = [&](int bi) {
            const char* Ar = lds[bi] + (wr * 32 + r) * 64;
            const char* Br = lds[bi] + 4096 + (wc * 64 + r) * 64;
            bf16x8 a0  = *(const bf16x8*)(Ar + off);
            bf16x8 a1  = *(const bf16x8*)(Ar + 1024 + off);
            bf16x8 b0  = *(const bf16x8*)(Br + off);
            bf16x8 b1r = *(const bf16x8*)(Br + 1024 + off);
            bf16x8 b2r = *(const bf16x8*)(Br + 2048 + off);
            bf16x8 b3r = *(const bf16x8*)(Br + 3072 + off);
            acc[0][0] = __builtin_amdgcn_mfma_f32_16x16x32_bf16(a0, b0,  acc[0][0], 0, 0, 0);
            acc[0][1] = __builtin_amdgcn_mfma_f32_16x16x32_bf16(a0, b1r, acc[0][1], 0, 0, 0);
            acc[0][2] = __builtin_amdgcn_mfma_f32_16x16x32_bf16(a0, b2r, acc[0][2], 0, 0, 0);
            acc[0][3] = __builtin_amdgcn_mfma_f32_16x16x32_bf16(a0, b3r, acc[0][3], 0, 0, 0);
            acc[1][0] = __builtin_amdgcn_mfma_f32_16x16x32_bf16(a1, b0,  acc[1][0], 0, 0, 0);
            acc[1][1] = __builtin_amdgcn_mfma_f32_16x16x32_bf16(a1, b1r, acc[1][1], 0, 0, 0);
            acc[1][2] = __builtin_amdgcn_mfma_f32_16x16x32_bf16(a1, b2r, acc[1][2], 0, 0, 0);
            acc[1][3] = __builtin_amdgcn_mfma_f32_16x16x32_bf16(a1, b3r, acc[1][3], 0, 0, 0);
        };

        __syncthreads();        // lds free from previous pass
        stage(0); stage(1);
        int cs = 2, cc = 0;
        #pragma unroll 1
        for (int it = 0; it < HD / BK - 2; ++it) {
            asm volatile("s_waitcnt vmcnt(3)" ::: "memory");
            __builtin_amdgcn_s_barrier();
            stage(cs); cs = (cs == 2) ? 0 : cs + 1;
            compute(cc); cc = (cc == 2) ? 0 : cc + 1;
        }
        asm volatile("s_waitcnt vmcnt(3)" ::: "memory");
        __builtin_amdgcn_s_barrier();
        compute(cc); cc = (cc == 2) ? 0 : cc + 1;
        asm volatile("s_waitcnt vmcnt(0)" ::: "memory");
        __builtin_amdgcn_s_barrier();
        compute(cc);

        // epilogue: bias + gelu + w2 partial dot + 16-lane reduce, masked to e's rows
        int lo = base[e];
        int hi = (e < NE - 1) ? base[e + 1] : BQ;
        float b1v[4], w20v[4], w21v[4];
        #pragma unroll
        for (int j = 0; j < 4; j++) {
            int col = n0 + wc * 64 + j * 16 + r;
            b1v[j]  = b1[e * HD + col];
            w20v[j] = w2[((size_t)e * HD + col) * 2 + 0];
            w21v[j] = w2[((size_t)e * HD + col) * 2 + 1];
        }
        #pragma unroll
        for (int i = 0; i < 2; i++) {
            #pragma unroll
            for (int reg = 0; reg < 4; reg++) {
                float s0 = 0.f, s1 = 0.f;
                #pragma unroll
                for (int j = 0; j < 4; j++) {
                    float hv = gelu_exact(acc[i][j][reg] + b1v[j]);
                    s0 += hv * w20v[j];
                    s1 += hv * w21v[j];
                }
                #pragma unroll
                for (int offx = 1; offx < 16; offx <<= 1) {
                    s0 += __shfl_xor(s0, offx);
                    s1 += __shfl_xor(s1, offx);
                }
                if (r == 0) {
                    int lm = wr * 32 + i * 16 + 4 * h + reg;
                    int p = p0 + lm;
                    if (p >= lo && p < hi) {
                        atomicAdd(&logits2c[p * 2 + 0], s0);
                        atomicAdd(&logits2c[p * 2 + 1], s1);
                    }
                }
            }
        }
    }
}

// ---------------- CE over (softmaxed) expert outputs (compacted order) --------
__global__ __launch_bounds__(256) void ce_kernel(
    const float* __restrict__ logits2c, const float* __restrict__ b2,
    const int* __restrict__ idx, const int* __restrict__ rowlist,
    const int* __restrict__ label, float* __restrict__ cesum)
{
    __shared__ float red[4];
    int tid = threadIdx.x;
    int p = blockIdx.x * 256 + tid;
    int rr = rowlist[p];
    int e = idx[rr];
    float l0 = logits2c[p * 2 + 0] + b2[e * 2 + 0];
    float l1 = logits2c[p * 2 + 1] + b2[e * 2 + 1];
    float mx = fmaxf(l0, l1);
    float e0 = expf(l0 - mx), e1 = expf(l1 - mx);
    float inv = 1.f / (e0 + e1);
    float p0 = e0 * inv, p1 = e1 * inv;
    float m2 = fmaxf(p0, p1);
    float z = m2 + logf(expf(p0 - m2) + expf(p1 - m2));
    float lp = ((label[rr] == 0) ? p0 : p1) - z;
    float ce = -lp;

    int lane = tid & 63, wave = tid >> 6;
    #pragma unroll
    for (int off = 32; off > 0; off >>= 1) ce += __shfl_xor(ce, off);
    if (lane == 0) red[wave] = ce;
    __syncthreads();
    if (tid == 0) atomicAdd(cesum, red[0] + red[1] + red[2] + red[3]);
}

// ---------------- finalize ----------------
__global__ void finalize_kernel(const float* __restrict__ S, const int* __restrict__ count,
                                const float* __restrict__ zsum, const float* __restrict__ cesum,
                                float* __restrict__ out)
{
    if (threadIdx.x == 0 && blockIdx.x == 0) {
        float bal = 0.f;
        for (int e = 0; e < NE; e++) bal += S[e] * (float)count[e];
        bal *= (float)NE / ((float)BQ * (float)BQ);
        out[0] = cesum[0] / (float)BQ + 0.01f * bal + 0.001f * (zsum[0] / (float)BQ);
    }
}

extern "C" void kernel_launch(void* const* d_in, const int* in_sizes, int n_in,
                              void* d_out, int out_size, void* d_ws, size_t ws_size,
                              hipStream_t stream) {
    const float* x      = (const float*)d_in[0];
    const int*   label  = (const int*)d_in[1];
    const float* gate_w = (const float*)d_in[2];
    const float* w1     = (const float*)d_in[3];
    const float* b1     = (const float*)d_in[4];
    const float* w2     = (const float*)d_in[5];
    const float* b2     = (const float*)d_in[6];
    float* out = (float*)d_out;

    char* ws = (char*)d_ws;
    int*   idx      = (int*)(ws + WS_IDX);
    int*   rowlist  = (int*)(ws + WS_ROWLIST);
    int*   dest     = (int*)(ws + WS_DEST);
    int*   count    = (int*)(ws + WS_COUNT);
    int*   base     = (int*)(ws + WS_BASE);
    int*   cursor   = (int*)(ws + WS_CURSOR);
    float* S        = (float*)(ws + WS_S);
    float* zsum     = (float*)(ws + WS_ZSUM);
    float* cesum    = (float*)(ws + WS_CESUM);
    int*   ticket   = (int*)(ws + WS_TICKET);
    float* logits2c = (float*)(ws + WS_LOGITS2);
    unsigned short* xc  = (unsigned short*)(ws + WS_XC);
    unsigned short* w1t = (unsigned short*)(ws + WS_W1T);

    hipMemsetAsync(d_ws, 0, WS_HEAD, stream);

    prep_kernel<<<2304, 256, 0, stream>>>(x, gate_w, w1, idx, count, S, zsum,
                                          ticket, base, cursor, w1t);
    scatter_kernel<<<BQ / 256, 256, 0, stream>>>(idx, cursor, rowlist, dest);
    compact_kernel<<<BQ / 4, 256, 0, stream>>>(x, dest, xc);
    expert_gemm_kernel<<<1024, 256, 0, stream>>>(xc, w1t, b1, w2, base, logits2c);
    ce_kernel<<<BQ / 256, 256, 0, stream>>>(logits2c, b2, idx, rowlist, label, cesum);
    finalize_kernel<<<1, 64, 0, stream>>>(S, count, zsum, cesum, out);
}